// Round 8
// baseline (11418.996 us; speedup 1.0000x reference)
//
#include <hip/hip_runtime.h>
#include <math.h>

#define DM   1024
#define BSZ  4
#define LSEQ 4096
#define GPB  32            // WGs per batch group (co-resident on one XCD)
#define RPW  32            // rows per WG (DM / GPB)
#define TPB  512
#define SEGC 64            // columns per thread segment
#define SSP  68            // padded words per 64-col segment
#define HSW2 1088          // 16 * SSP : staged-state words per buffer

typedef unsigned long long u64;

// ---------------- Phase 1: bx = x @ B_w^T (fp32 NT GEMM) ----------------
__global__ __launch_bounds__(256) void bx_gemm_kernel(
    const float* __restrict__ X, const float* __restrict__ Bw,
    float* __restrict__ out)
{
    __shared__ float xs[16][68];
    __shared__ float bs[16][68];
    const int bm = blockIdx.x, bn = blockIdx.y;
    const int t  = threadIdx.x;
    const int tx = t & 15, ty = t >> 4;
    const int ml = t >> 2;
    const int kq = (t & 3) * 4;
    const float* xg = X  + (size_t)(bm * 64 + ml) * DM + kq;
    const float* bg = Bw + (size_t)(bn * 64 + ml) * DM + kq;
    float acc[4][4] = {};
    for (int k0 = 0; k0 < DM; k0 += 16) {
        float4 xv = *(const float4*)(xg + k0);
        float4 bv = *(const float4*)(bg + k0);
        __syncthreads();
        xs[kq+0][ml] = xv.x; xs[kq+1][ml] = xv.y; xs[kq+2][ml] = xv.z; xs[kq+3][ml] = xv.w;
        bs[kq+0][ml] = bv.x; bs[kq+1][ml] = bv.y; bs[kq+2][ml] = bv.z; bs[kq+3][ml] = bv.w;
        __syncthreads();
        #pragma unroll
        for (int kk = 0; kk < 16; ++kk) {
            float a[4], c[4];
            #pragma unroll
            for (int i = 0; i < 4; ++i) a[i] = xs[kk][ty*4+i];
            #pragma unroll
            for (int j = 0; j < 4; ++j) c[j] = bs[kk][tx*4+j];
            #pragma unroll
            for (int i = 0; i < 4; ++i)
                #pragma unroll
                for (int j = 0; j < 4; ++j)
                    acc[i][j] += a[i] * c[j];
        }
    }
    #pragma unroll
    for (int i = 0; i < 4; ++i) {
        float4 v = make_float4(acc[i][0], acc[i][1], acc[i][2], acc[i][3]);
        *(float4*)(out + (size_t)(bm*64 + ty*4 + i)*DM + bn*64 + tx*4) = v;
    }
}

// Poll one tagged word: fast copy (XCD-L2, RMW-read) with bounded retries,
// then safe copy (agent/MALL). Latches fastok=0 if the fast copy provably
// never received a value the safe copy already has.
__device__ __forceinline__ u64 poll_word(u64* fast, u64* safe, unsigned tag,
                                         u64 v, int& fastok)
{
    if ((unsigned)(v >> 32) == tag) return v;
    if (fastok) {
        #pragma unroll 1
        for (int i = 0; i < 16; ++i) {
            v = __hip_atomic_fetch_add(fast, 0ULL, __ATOMIC_RELAXED,
                                       __HIP_MEMORY_SCOPE_WORKGROUP);
            if ((unsigned)(v >> 32) == tag) return v;
        }
    }
    int spins = 0;
    do {
        v = __hip_atomic_load(safe, __ATOMIC_RELAXED, __HIP_MEMORY_SCOPE_AGENT);
    } while ((unsigned)(v >> 32) != tag && ++spins < (1 << 20));
    if (fastok) {
        u64 f = __hip_atomic_fetch_add(fast, 0ULL, __ATOMIC_RELAXED,
                                       __HIP_MEMORY_SCOPE_WORKGROUP);
        if ((unsigned)(f >> 32) != tag) fastok = 0;   // fast path dead
    }
    return v;
}

// fast tanh: 1 - 2/(e^{2x}+1); exact saturation at +/-inf of exp
__device__ __forceinline__ float fast_tanh(float x)
{
    float e = __expf(2.0f * x);
    return (e - 1.0f) / (e + 1.0f);
}

// ---------------- Phase 2: fused scan, XCD-local tagged exchange ----------
// 256 WGs launched; residue r=blockIdx&7: r<4 -> batch group r (32 WGs on
// XCD r under round-robin dispatch), r>=4 -> exit. A and C row-slices BOTH
// in registers (64 floats each per thread); LDS holds only the staged-h
// double buffer (8.7KB). Single fused pass over staged h computes accA and
// accC together (one set of LDS reads, 2 FMA chains, ~2-way conflicts only).
// State = (tag<<32|float) u64 dual copy: fast (wg-scope, XCD L2) + safe
// (agent scope, MALL fallback). hs double-buffered, one barrier per step.
__global__ __launch_bounds__(TPB, 2) void scan_kernel(
    const float* __restrict__ A, const float* __restrict__ Cw,
    const float* __restrict__ Dv, const float* __restrict__ X,
    float* __restrict__ Y, u64* hfast, u64* hsafe)
{
    const int r = blockIdx.x & 7;
    if (r >= BSZ) return;                    // 128 WGs exit immediately
    const int b  = r;                        // batch group
    const int gw = blockIdx.x >> 3;          // 0..31 within group
    const int r0 = gw * RPW;

    __shared__ float hs0[2 * HSW2];          // staged h, double-buffered
    const int t   = threadIdx.x;
    const int row = t >> 4;                  // 0..31
    const int seg = t & 15;                  // 64-col segment
    const bool lead = (seg == 0);

    // A and C row-slices -> registers (64 floats each)
    float ra[SEGC], rc[SEGC];
    {
        const float* Ap = A  + (size_t)(r0 + row) * DM + seg * SEGC;
        const float* Cp = Cw + (size_t)(r0 + row) * DM + seg * SEGC;
        #pragma unroll
        for (int u = 0; u < SEGC / 4; ++u) {
            float4 v = *(const float4*)(Ap + u*4);
            ra[u*4+0]=v.x; ra[u*4+1]=v.y; ra[u*4+2]=v.z; ra[u*4+3]=v.w;
            float4 w = *(const float4*)(Cp + u*4);
            rc[u*4+0]=w.x; rc[u*4+1]=w.y; rc[u*4+2]=w.z; rc[u*4+3]=w.w;
        }
    }
    const float dv = Dv[r0 + row];

    const int c0 = t, c1 = t + 512;
    const int s0 = (c0 >> 6) * SSP + (c0 & 63);
    const int s1 = (c1 >> 6) * SSP + (c1 & 63);
    int fastok = 1;

    // prologue spec for k=0: SAFE copy only (stale fast lines may survive
    // graph replays in XCD L2; safe copy is freshly memset through MALL)
    u64 v0 = __hip_atomic_load(hsafe + (size_t)b * DM + c0, __ATOMIC_RELAXED, __HIP_MEMORY_SCOPE_AGENT);
    u64 v1 = __hip_atomic_load(hsafe + (size_t)b * DM + c1, __ATOMIC_RELAXED, __HIP_MEMORY_SCOPE_AGENT);
    float bxv = 0.f;          // bx_k    (tanh input at iteration k)
    float xv  = 0.f;          // x_{k-1} (y-store at iteration k)
    if (lead) bxv = Y[(size_t)b*LSEQ*DM + r0 + row];

    for (int k = 0; k <= LSEQ; ++k) {
        const unsigned tag = (unsigned)k;
        const size_t slot = (size_t)(k & 1) * BSZ * DM + (size_t)b * DM;
        int dummy = 0;
        int& fo = (k == 0) ? dummy : fastok;

        // ---- finish poll for s_k (spec loads issued last iteration) ----
        v0 = poll_word(hfast + slot + c0, hsafe + slot + c0, tag, v0, fo);
        v1 = poll_word(hfast + slot + c1, hsafe + slot + c1, tag, v1, fo);

        float* hsk = hs0 + (k & 1) * HSW2;
        hsk[s0] = __uint_as_float((unsigned)v0);
        hsk[s1] = __uint_as_float((unsigned)v1);
        __syncthreads();   // the only barrier per step

        // ---- fused A+C matvec: one pass over staged h ----
        float accA = 0.f, accC = 0.f;
        {
            const float4* h4p = (const float4*)(hsk + seg * SSP);
            #pragma unroll
            for (int u = 0; u < SEGC / 4; ++u) {
                float4 h4 = h4p[u];
                accA += ra[u*4+0]*h4.x + ra[u*4+1]*h4.y + ra[u*4+2]*h4.z + ra[u*4+3]*h4.w;
                accC += rc[u*4+0]*h4.x + rc[u*4+1]*h4.y + rc[u*4+2]*h4.z + rc[u*4+3]*h4.w;
            }
        }

        float xv_next = xv;
        if (k < LSEQ) {
            // ---- critical path: reduce accA, tanh, dual h-store ----
            accA += __shfl_xor(accA, 1);
            accA += __shfl_xor(accA, 2);
            accA += __shfl_xor(accA, 4);
            accA += __shfl_xor(accA, 8);
            const size_t nslot = (size_t)((k+1) & 1) * BSZ * DM + (size_t)b * DM;
            if (lead) {
                float hv = fast_tanh(accA + bxv);
                u64 pk = ((u64)(unsigned)(k + 1) << 32) | (u64)__float_as_uint(hv);
                __hip_atomic_store(hfast + nslot + r0 + row, pk,
                                   __ATOMIC_RELAXED, __HIP_MEMORY_SCOPE_WORKGROUP);
                __hip_atomic_store(hsafe + nslot + r0 + row, pk,
                                   __ATOMIC_RELAXED, __HIP_MEMORY_SCOPE_AGENT);
            }
            // ---- issue speculative polls for step k+1 immediately ----
            if (fastok) {
                v0 = __hip_atomic_fetch_add(hfast + nslot + c0, 0ULL,
                                            __ATOMIC_RELAXED, __HIP_MEMORY_SCOPE_WORKGROUP);
                v1 = __hip_atomic_fetch_add(hfast + nslot + c1, 0ULL,
                                            __ATOMIC_RELAXED, __HIP_MEMORY_SCOPE_WORKGROUP);
            } else {
                v0 = __hip_atomic_load(hsafe + nslot + c0, __ATOMIC_RELAXED, __HIP_MEMORY_SCOPE_AGENT);
                v1 = __hip_atomic_load(hsafe + nslot + c1, __ATOMIC_RELAXED, __HIP_MEMORY_SCOPE_AGENT);
            }
            // prefetch next-step operands (off critical path)
            if (lead) {
                xv_next = X[(size_t)b*LSEQ*DM + (size_t)k*DM + r0 + row];   // x_k
                if (k + 1 < LSEQ)
                    bxv = Y[(size_t)b*LSEQ*DM + (size_t)(k+1)*DM + r0 + row];
            }
        }

        // ---- deferred: reduce accC + y-store (overlaps next poll) ----
        if (k > 0) {
            accC += __shfl_xor(accC, 1);
            accC += __shfl_xor(accC, 2);
            accC += __shfl_xor(accC, 4);
            accC += __shfl_xor(accC, 8);
            if (lead) {
                const size_t yoff = (size_t)b*LSEQ*DM + (size_t)(k-1)*DM + r0 + row;
                Y[yoff] = accC + dv * xv;        // y_{k-1} = C s_k + D x_{k-1}
            }
        }
        xv = xv_next;
    }
}

extern "C" void kernel_launch(void* const* d_in, const int* in_sizes, int n_in,
                              void* d_out, int out_size, void* d_ws, size_t ws_size,
                              hipStream_t stream)
{
    const float* X  = (const float*)d_in[0];
    const float* A  = (const float*)d_in[1];
    const float* Bw = (const float*)d_in[2];
    const float* Cw = (const float*)d_in[3];
    const float* Dv = (const float*)d_in[4];
    float* Y    = (float*)d_out;
    u64* hfast  = (u64*)d_ws;
    u64* hsafe  = hfast + (size_t)2 * BSZ * DM;

    // zero both tagged copies every launch: (0.0f, tag 0) == s_0 ready
    hipMemsetAsync(d_ws, 0, (size_t)4 * BSZ * DM * sizeof(u64), stream);

    dim3 g1((BSZ * LSEQ) / 64, DM / 64);
    bx_gemm_kernel<<<g1, 256, 0, stream>>>(X, Bw, Y);
    scan_kernel<<<256, TPB, 0, stream>>>(A, Cw, Dv, X, Y, hfast, hsafe);
}